// Round 2
// baseline (1142.556 us; speedup 1.0000x reference)
//
#include <hip/hip_runtime.h>

#define B_TOT 8192
#define NN 64
#define FF 32
#define ITERS 48
#define THRESH 0.35f
#define WPB 4   // waves (= independent batches) per 256-thread block

typedef float vf64 __attribute__((ext_vector_type(64)));

// ws layout: [0..3] int Tmax (atomicMax target, memset to 0 each launch),
//            [16 .. 16 + B*48) unsigned char selection indices per batch.

__global__ __launch_bounds__(64 * WPB, 5) void gat_greedy_kernel(
    const float* __restrict__ mail,
    const float* __restrict__ attn_w,
    const float* __restrict__ src_norm,
    int* __restrict__ tmax_ws,
    unsigned char* __restrict__ sels_ws)
{
    const int wave = threadIdx.x >> 6;
    const int lane = threadIdx.x & 63;
    const int b = blockIdx.x * WPB + wave;
    // wave-uniform batch index as SGPR so row-m loads go down the s_load path
    const int bu = __builtin_amdgcn_readfirstlane(b);
    const float* __restrict__ brow = mail + (size_t)bu * (NN * FF);

    __shared__ float2 qs[WPB][NN];                    // (|a|^2, src_norm) per node
    __shared__ __align__(16) float c_lds[WPB][NN];    // greedy cache, per wave

    const float sn = src_norm[b * NN + lane];

    // ---- chunk-streamed Gram: srow[m] += <a_lane, a_m> ; q and logit alongside.
    // Sequential-f accumulation order is identical for q and for g_nm, so the
    // diagonal g_nn == q bitwise (row m==lane loads the same bits as a4).
    vf64 srow;
#pragma unroll
    for (int m = 0; m < NN; ++m) srow[m] = 0.f;
    float q = 0.f, lg = 0.f;
#pragma unroll 1
    for (int k = 0; k < 8; ++k) {
        const float4 a4 = *reinterpret_cast<const float4*>(brow + lane * FF + 4 * k);
        const float4 w4 = *reinterpret_cast<const float4*>(attn_w + 4 * k);
        q  = fmaf(a4.x, a4.x, q);  q  = fmaf(a4.y, a4.y, q);
        q  = fmaf(a4.z, a4.z, q);  q  = fmaf(a4.w, a4.w, q);
        lg = fmaf(a4.x, w4.x, lg); lg = fmaf(a4.y, w4.y, lg);
        lg = fmaf(a4.z, w4.z, lg); lg = fmaf(a4.w, w4.w, lg);
#pragma unroll
        for (int m = 0; m < NN; ++m) {
            const float4 r4 = *reinterpret_cast<const float4*>(brow + m * FF + 4 * k);
            float g = srow[m];
            g = fmaf(a4.x, r4.x, g); g = fmaf(a4.y, r4.y, g);
            g = fmaf(a4.z, r4.z, g); g = fmaf(a4.w, r4.w, g);
            srow[m] = g;
        }
    }
    lg *= sn;

    qs[wave][lane] = make_float2(q, sn);
    c_lds[wave][lane] = 0.f;
    __syncthreads();

    // ---- softmax over 64 neighbors (wave butterfly) ----
    float mx = lg;
#pragma unroll
    for (int off = 32; off > 0; off >>= 1)
        mx = fmaxf(mx, __shfl_xor(mx, off, 64));
    const float ex = __expf(lg - mx);
    float se = ex;
#pragma unroll
    for (int off = 32; off > 0; off >>= 1)
        se += __shfl_xor(se, off, 64);
    const float attn = ex / se;

    // ---- distances from Gram; keep d in srow regs ----
    const float sqn = sn * sn * q;
    float dsum = 0.f;
#pragma unroll
    for (int m = 0; m < NN; ++m) {
        const float2 qsm = qs[wave][m];          // uniform ds_read_b64 broadcast
        const float qm = qsm.x, sm = qsm.y;
        const float sqm = sm * sm * qm;
        const float d2  = (sqn - 2.f * (sn * sm) * srow[m]) + sqm;
        const float d   = sqrtf(fmaxf(d2, 0.f));
        dsum += d;
        srow[m] = d;
    }
    float tot = dsum;
#pragma unroll
    for (int off = 32; off > 0; off >>= 1)
        tot += __shfl_xor(tot, off, 64);
    const float meand = tot * (1.f / (float)(NN * NN));
    const float inv   = -1.f / meand;            // SIGMA = 1

#pragma unroll
    for (int m = 0; m < NN; ++m) srow[m] = __expf(srow[m] * inv);

    // ---- greedy loop ----
    float c_reg = 0.f;
    int firstBelow = ITERS;
    bool seenBelow = false;
    bool done = false;
    unsigned char* __restrict__ sb = sels_ws + (size_t)b * ITERS;

    for (int t = 0; t < ITERS; ++t) {
        if (!done) {
            // gain_n = attn_n * sum_m relu(s_nm - c_m), sequential-m order
            float gain = 0.f;
#pragma unroll
            for (int kk = 0; kk < 16; ++kk) {
                const float4 cv = reinterpret_cast<const float4*>(&c_lds[wave][0])[kk];
                gain += fmaxf(srow[4 * kk + 0] - cv.x, 0.f);
                gain += fmaxf(srow[4 * kk + 1] - cv.y, 0.f);
                gain += fmaxf(srow[4 * kk + 2] - cv.z, 0.f);
                gain += fmaxf(srow[4 * kk + 3] - cv.w, 0.f);
            }
            gain *= attn;

            // argmax, FIRST-index tie-break (matches jnp.argmax)
            float gv = gain; int gi = lane;
#pragma unroll
            for (int off = 32; off > 0; off >>= 1) {
                const float ov = __shfl_xor(gv, off, 64);
                const int   oi = __shfl_xor(gi, off, 64);
                if (ov > gv || (ov == gv && oi < gi)) { gv = ov; gi = oi; }
            }

            if (!seenBelow && gv < THRESH) { firstBelow = t; seenBelow = true; }

            if (gv == 0.0f) {
                // saturated: all gains exactly 0 forever -> argmax stays 0,
                // cache frozen. Fill remaining sels and idle through barriers.
                if (lane == 0)
                    for (int t2 = t; t2 < ITERS; ++t2) sb[t2] = 0;
                done = true;
            } else {
                if (lane == 0) sb[t] = (unsigned char)gi;
                // cache update via symmetry: s_{sel,lane} == s_{lane,sel} ==
                // own-register row at wave-uniform index -> v_movrels extract.
                const int sel = __builtin_amdgcn_readfirstlane(gi);
                const float srl = srow[sel];
                c_reg = fmaxf(c_reg, srl);
                c_lds[wave][lane] = c_reg;
            }
        }
        if (__syncthreads_and((int)done)) break;   // doubles as the iter barrier
    }

    if (lane == 0) atomicMax(tmax_ws, firstBelow);
}

__global__ __launch_bounds__(256) void gat_accum_kernel(
    const float* __restrict__ mail,
    const float* __restrict__ src_norm,
    const float* __restrict__ dst_norm,
    const int* __restrict__ tmax_ws,
    const unsigned char* __restrict__ sels_ws,
    float* __restrict__ out)
{
    const int lane = threadIdx.x & 31;
    const int b = blockIdx.x * 8 + (threadIdx.x >> 5);
    const int C = min(ITERS, *tmax_ws + 1);   // append-then-check

    // preload all 48 selection bytes -> the 48 gathers below are independent
    const uint4* sp = reinterpret_cast<const uint4*>(sels_ws + (size_t)b * ITERS);
    const uint4 w0 = sp[0], w1 = sp[1], w2 = sp[2];
    unsigned int wds[12] = { w0.x, w0.y, w0.z, w0.w,
                             w1.x, w1.y, w1.z, w1.w,
                             w2.x, w2.y, w2.z, w2.w };
    float acc = 0.f;
#pragma unroll
    for (int d = 0; d < 12; ++d) {
        const int tbase = 4 * d;
        if (tbase < C) {
            const unsigned int wv = wds[d];
#pragma unroll
            for (int j = 0; j < 4; ++j) {
                if (tbase + j < C) {
                    const int sel = (wv >> (8 * j)) & 0xFF;
                    acc = fmaf(mail[((size_t)b * NN + sel) * FF + lane],
                               src_norm[b * NN + sel], acc);
                }
            }
        }
    }
    out[b * FF + lane] = acc * dst_norm[b];
}

extern "C" void kernel_launch(void* const* d_in, const int* in_sizes, int n_in,
                              void* d_out, int out_size, void* d_ws, size_t ws_size,
                              hipStream_t stream)
{
    const float* mail     = (const float*)d_in[0];
    const float* attn_w   = (const float*)d_in[1];
    const float* src_norm = (const float*)d_in[2];
    const float* dst_norm = (const float*)d_in[3];
    float* out = (float*)d_out;

    int* tmax_ws = (int*)d_ws;
    unsigned char* sels_ws = (unsigned char*)d_ws + 16;

    hipMemsetAsync(d_ws, 0, 4, stream);   // zero the Tmax word
    gat_greedy_kernel<<<dim3(B_TOT / WPB), dim3(64 * WPB), 0, stream>>>(
        mail, attn_w, src_norm, tmax_ws, sels_ws);
    gat_accum_kernel<<<dim3(B_TOT / 8), dim3(256), 0, stream>>>(
        mail, src_norm, dst_norm, tmax_ws, sels_ws, out);
}

// Round 6
// 413.501 us; speedup vs baseline: 2.7631x; 2.7631x over previous
//
#include <hip/hip_runtime.h>

#define B_TOT 8192
#define NN 64
#define FF 32
#define ITERS 48
#define THRESH 0.35f

// ws layout: [0..3] int Tmax (atomicMax target, memset to 0 each launch),
//            [16 .. 16 + B*48) unsigned char selection indices per batch.

__global__ __launch_bounds__(64, 4) void gat_greedy_kernel(
    const float* __restrict__ mail,
    const float* __restrict__ attn_w,
    const float* __restrict__ src_norm,
    int* __restrict__ tmax_ws,
    unsigned char* __restrict__ sels_ws)
{
    const int b = blockIdx.x;
    const int lane = threadIdx.x;

    // sims row stride 65: lane-varying reads sims[sel*65+lane] hit banks
    // (sel+lane)%32 -> 2-way aliasing only (free on CDNA4).
    __shared__ __align__(16) float sims[NN * 65];
    __shared__ __align__(16) float c_lds[NN];
    __shared__ float qarr[NN];
    __shared__ float sarr[NN];

    // ---- load own raw mail row into registers ----
    const float* __restrict__ myrow = mail + ((size_t)b * NN + lane) * FF;
    float a[FF];
#pragma unroll
    for (int k = 0; k < 8; ++k) {
        const float4 v = reinterpret_cast<const float4*>(myrow)[k];
        a[4*k+0] = v.x; a[4*k+1] = v.y; a[4*k+2] = v.z; a[4*k+3] = v.w;
    }
    const float sn = src_norm[b * NN + lane];

    // |a|^2 with the SAME 4-accumulator tree as the dot below (diag consistency)
    float q0 = 0.f, q1 = 0.f, q2 = 0.f, q3 = 0.f;
#pragma unroll
    for (int k = 0; k < 8; ++k) {
        q0 = fmaf(a[4*k+0], a[4*k+0], q0);
        q1 = fmaf(a[4*k+1], a[4*k+1], q1);
        q2 = fmaf(a[4*k+2], a[4*k+2], q2);
        q3 = fmaf(a[4*k+3], a[4*k+3], q3);
    }
    const float q = (q0 + q1) + (q2 + q3);

    // logits: (sigma_n * a_n) . w  computed as sigma_n * (a_n . w)
    float lg = 0.f;
#pragma unroll
    for (int f = 0; f < FF; ++f) lg = fmaf(a[f], attn_w[f], lg);
    lg *= sn;

    qarr[lane] = q;
    sarr[lane] = sn;
    __syncthreads();

    // ---- softmax over the 64 neighbors (wave butterfly) ----
    float mx = lg;
#pragma unroll
    for (int off = 32; off > 0; off >>= 1)
        mx = fmaxf(mx, __shfl_xor(mx, off, 64));
    const float ex = __expf(lg - mx);
    float se = ex;
#pragma unroll
    for (int off = 32; off > 0; off >>= 1)
        se += __shfl_xor(se, off, 64);
    const float attn = ex / se;

    // ---- pairwise distances: lane n computes row n via Gram trick.
    // Row m operand address is wave-uniform -> scalar (s_load) path.
    const float sqn = sn * sn * q;
    float dsum = 0.f;
    for (int m = 0; m < NN; ++m) {
        const float4* __restrict__ Am =
            reinterpret_cast<const float4*>(mail + ((size_t)b * NN + m) * FF);
        float g0 = 0.f, g1 = 0.f, g2 = 0.f, g3 = 0.f;
#pragma unroll
        for (int k = 0; k < 8; ++k) {
            const float4 v = Am[k];
            g0 = fmaf(a[4*k+0], v.x, g0);
            g1 = fmaf(a[4*k+1], v.y, g1);
            g2 = fmaf(a[4*k+2], v.z, g2);
            g3 = fmaf(a[4*k+3], v.w, g3);
        }
        const float g  = (g0 + g1) + (g2 + g3);
        const float sm = sarr[m];
        const float qm = qarr[m];
        const float sqm = sm * sm * qm;
        const float d2  = (sqn - 2.f * (sn * sm) * g) + sqm;
        const float d   = sqrtf(fmaxf(d2, 0.f));
        dsum += d;
        sims[lane * 65 + m] = d;   // stash distance; exp applied after mean known
    }

    // per-batch mean distance
    float tot = dsum;
#pragma unroll
    for (int off = 32; off > 0; off >>= 1)
        tot += __shfl_xor(tot, off, 64);
    const float meand = tot * (1.f / (float)(NN * NN));
    const float inv   = -1.f / meand;   // SIGMA = 1

    // sims = exp(-d/mean); keep a register copy of own row for the greedy loop
    float srow[NN];
#pragma unroll
    for (int m = 0; m < NN; ++m) {
        const float d = sims[lane * 65 + m];
        const float s = __expf(d * inv);
        srow[m] = s;
        sims[lane * 65 + m] = s;
    }

    c_lds[lane] = 0.f;
    float c_reg = 0.f;
    __syncthreads();

    // ---- greedy loop (r1 dataflow; cache-update value ALWAYS from the LDS
    //      sims row read — the empirically proven path) ----
    int firstBelow = ITERS;
    bool seenBelow = false;
    unsigned char* __restrict__ sb = sels_ws + (size_t)b * ITERS;

    for (int t = 0; t < ITERS; ++t) {
        // gain_n = attn_n * sum_m relu(s_nm - c_m)   (reference-accurate form)
        float gain = 0.f;
#pragma unroll
        for (int k = 0; k < 16; ++k) {
            const float4 cv = reinterpret_cast<const float4*>(c_lds)[k];  // uniform b128 broadcast
            gain += fmaxf(srow[4*k+0] - cv.x, 0.f);
            gain += fmaxf(srow[4*k+1] - cv.y, 0.f);
            gain += fmaxf(srow[4*k+2] - cv.z, 0.f);
            gain += fmaxf(srow[4*k+3] - cv.w, 0.f);
        }
        gain *= attn;

        // argmax with FIRST-index tie-break (matches jnp.argmax, incl. all-zero tail)
        float gv = gain; int gi = lane;
#pragma unroll
        for (int off = 32; off > 0; off >>= 1) {
            const float ov = __shfl_xor(gv, off, 64);
            const int   oi = __shfl_xor(gi, off, 64);
            if (ov > gv || (ov == gv && oi < gi)) { gv = ov; gi = oi; }
        }

        if (!seenBelow && gv < THRESH) { firstBelow = t; seenBelow = true; }

        if (gv == 0.0f) {
            // saturated (r2-proven): all gains exactly 0 forever -> argmax
            // stays 0, cache update is a no-op. Fill remaining sels, stop.
            if (lane == 0)
                for (int t2 = t; t2 < ITERS; ++t2) sb[t2] = 0;
            break;
        }

        if (lane == 0) sb[t] = (unsigned char)gi;

        // cache update: lane m handles column m (conflict-free stride-65 read)
        const float srl = sims[gi * 65 + lane];
        c_reg = fmaxf(c_reg, srl);
        c_lds[lane] = c_reg;
        __syncthreads();   // single-wave block: cheap; guards LDS RAW ordering
    }

    if (lane == 0) atomicMax(tmax_ws, firstBelow);
}

__global__ __launch_bounds__(256) void gat_accum_kernel(
    const float* __restrict__ mail,
    const float* __restrict__ src_norm,
    const float* __restrict__ dst_norm,
    const int* __restrict__ tmax_ws,
    const unsigned char* __restrict__ sels_ws,
    float* __restrict__ out)
{
    const int lane = threadIdx.x & 31;
    const int b = blockIdx.x * 8 + (threadIdx.x >> 5);
    const int C = min(ITERS, *tmax_ws + 1);   // append-then-check

    // preload all 48 selection bytes -> the gathers below are independent
    const uint4* sp = reinterpret_cast<const uint4*>(sels_ws + (size_t)b * ITERS);
    const uint4 w0 = sp[0], w1 = sp[1], w2 = sp[2];
    unsigned int wds[12] = { w0.x, w0.y, w0.z, w0.w,
                             w1.x, w1.y, w1.z, w1.w,
                             w2.x, w2.y, w2.z, w2.w };
    float acc = 0.f;
#pragma unroll
    for (int d = 0; d < 12; ++d) {
        const int tbase = 4 * d;
        if (tbase < C) {
            const unsigned int wv = wds[d];
#pragma unroll
            for (int j = 0; j < 4; ++j) {
                if (tbase + j < C) {
                    const int sel = (wv >> (8 * j)) & 0xFF;
                    acc = fmaf(mail[((size_t)b * NN + sel) * FF + lane],
                               src_norm[b * NN + sel], acc);
                }
            }
        }
    }
    out[b * FF + lane] = acc * dst_norm[b];
}

extern "C" void kernel_launch(void* const* d_in, const int* in_sizes, int n_in,
                              void* d_out, int out_size, void* d_ws, size_t ws_size,
                              hipStream_t stream)
{
    const float* mail     = (const float*)d_in[0];
    const float* attn_w   = (const float*)d_in[1];
    const float* src_norm = (const float*)d_in[2];
    const float* dst_norm = (const float*)d_in[3];
    float* out = (float*)d_out;

    int* tmax_ws = (int*)d_ws;
    unsigned char* sels_ws = (unsigned char*)d_ws + 16;

    hipMemsetAsync(d_ws, 0, 4, stream);   // zero the Tmax word
    gat_greedy_kernel<<<dim3(B_TOT), dim3(64), 0, stream>>>(
        mail, attn_w, src_norm, tmax_ws, sels_ws);
    gat_accum_kernel<<<dim3(B_TOT / 8), dim3(256), 0, stream>>>(
        mail, src_norm, dst_norm, tmax_ws, sels_ws, out);
}